// Round 1
// 791.462 us; speedup vs baseline: 1.0898x; 1.0898x over previous
//
#include <hip/hip_runtime.h>
#include <cstdint>
#include <cstddef>

#define NTOK 8192
#define DMODEL 1024
#define NEXP 8
#define CAP 2048
#define HFF 2730
#define HFF2 5460
#define KPAD 2752

typedef float f32x4 __attribute__((ext_vector_type(4)));
typedef __attribute__((ext_vector_type(8))) short short8;

__device__ inline unsigned short f2bf(float f) {
  union { float f; unsigned u; } v; v.f = f;
  unsigned u = v.u;
  return (unsigned short)((u + 0x7FFFu + ((u >> 16) & 1u)) >> 16);
}
__device__ inline float bf2f(unsigned short s) {
  union { unsigned u; float f; } v; v.u = ((unsigned)s) << 16; return v.f;
}

// global -> LDS direct DMA, 16 B per lane. LDS dest: wave-uniform base + lane*16.
typedef __attribute__((address_space(1))) const void g_void;
typedef __attribute__((address_space(3))) void l_void;
__device__ __forceinline__ void dma16(const void* g, void* l) {
  __builtin_amdgcn_global_load_lds((g_void*)g, (l_void*)l, 16, 0, 0);
}

// ---------------- cast x f32 -> bf16 (stored in d_out scratch region) ----------------
__global__ void cast_x_kernel(const float* __restrict__ x, unsigned short* __restrict__ xb) {
  size_t i = ((size_t)blockIdx.x * 256 + threadIdx.x) * 8;
  float4 v0 = *(const float4*)(x + i);
  float4 v1 = *(const float4*)(x + i + 4);
  union { short8 v; unsigned short s[8]; } p;
  p.s[0] = f2bf(v0.x); p.s[1] = f2bf(v0.y); p.s[2] = f2bf(v0.z); p.s[3] = f2bf(v0.w);
  p.s[4] = f2bf(v1.x); p.s[5] = f2bf(v1.y); p.s[6] = f2bf(v1.z); p.s[7] = f2bf(v1.w);
  *(short8*)(xb + i) = p.v;
}

// ---------------- Router: one wave per token, fp64 accumulation ----------------
__global__ void router_kernel(const float* __restrict__ x,
                              const float* __restrict__ noise,
                              const float* __restrict__ w_route,
                              const float* __restrict__ b_route,
                              const float* __restrict__ w_noise,
                              const float* __restrict__ b_noise,
                              int* __restrict__ topi,
                              float* __restrict__ gates) {
  const int lane = threadIdx.x & 63;
  const int wave = threadIdx.x >> 6;
  const int tok = blockIdx.x * 4 + wave;
  const float* xr = x + (size_t)tok * DMODEL;

  double aR[8], aN[8];
#pragma unroll
  for (int e = 0; e < 8; e++) { aR[e] = 0.0; aN[e] = 0.0; }

  for (int d = lane; d < DMODEL; d += 64) {
    double xv = (double)xr[d];
    const float* wr = w_route + d * 8;
    const float* wn = w_noise + d * 8;
#pragma unroll
    for (int e = 0; e < 8; e++) {
      aR[e] += xv * (double)wr[e];
      aN[e] += xv * (double)wn[e];
    }
  }
#pragma unroll
  for (int off = 32; off > 0; off >>= 1) {
#pragma unroll
    for (int e = 0; e < 8; e++) {
      aR[e] += __shfl_down(aR[e], (unsigned)off, 64);
      aN[e] += __shfl_down(aN[e], (unsigned)off, 64);
    }
  }
  if (lane == 0) {
    double nv[8];
#pragma unroll
    for (int e = 0; e < 8; e++) {
      double lg = aR[e] + (double)b_route[e];
      double ns = aN[e] + (double)b_noise[e];
      double sp = fmax(ns, 0.0) + log1p(exp(-fabs(ns)));  // stable softplus
      nv[e] = lg + (double)noise[(size_t)tok * 8 + e] * sp;
    }
    int i0 = 0;
#pragma unroll
    for (int e = 1; e < 8; e++) if (nv[e] > nv[i0]) i0 = e;
    int i1 = (i0 == 0) ? 1 : 0;
#pragma unroll
    for (int e = 0; e < 8; e++) if (e != i0 && nv[e] > nv[i1]) i1 = e;
    double r = exp(nv[i1] - nv[i0]);
    float g0 = (float)(1.0 / (1.0 + r));
    float g1 = (float)(r / (1.0 + r));
    topi[tok * 2] = i0; topi[tok * 2 + 1] = i1;
    gates[tok * 2] = g0; gates[tok * 2 + 1] = g1;
  }
}

// ---------------- Aux loss ----------------
__global__ void aux_kernel(const int* __restrict__ topi,
                           const float* __restrict__ gates,
                           float* __restrict__ out) {
  const int t = threadIdx.x;
  float s[8];
#pragma unroll
  for (int e = 0; e < 8; e++) s[e] = 0.f;
  for (int i = t; i < NTOK; i += 256) {
    int i0 = topi[2 * i], i1 = topi[2 * i + 1];
    float g0 = gates[2 * i], g1 = gates[2 * i + 1];
#pragma unroll
    for (int e = 0; e < 8; e++)
      s[e] += (i0 == e ? g0 : 0.f) + (i1 == e ? g1 : 0.f);
  }
  __shared__ float sh[256][8];
#pragma unroll
  for (int e = 0; e < 8; e++) sh[t][e] = s[e];
  __syncthreads();
  for (int stride = 128; stride > 0; stride >>= 1) {
    if (t < stride) {
#pragma unroll
      for (int e = 0; e < 8; e++) sh[t][e] += sh[t + stride][e];
    }
    __syncthreads();
  }
  if (t == 0) {
    float aux = 0.f;
#pragma unroll
    for (int e = 0; e < 8; e++) {
      float p = sh[0][e] / (float)NTOK - 0.125f;
      aux += p * p;
    }
    out[(size_t)NTOK * DMODEL] = aux;
  }
}

// ---------------- Dispatch: per-expert ordered capacity scan + slot map ----------------
__global__ void dispatch_kernel(const int* __restrict__ topi,
                                const float* __restrict__ gates,
                                int* __restrict__ sel,
                                float* __restrict__ gsel,
                                int* __restrict__ slot) {
  const int e = blockIdx.x;
  const int t = threadIdx.x;
  const int lane = t & 63;
  const int w = t >> 6;
  __shared__ int waveCnt[16];
  __shared__ int runningS;
  if (t == 0) runningS = 0;
  __syncthreads();

  for (int base = 0; base < NTOK; base += 1024) {
    int tok = base + t;
    int i0 = topi[2 * tok], i1 = topi[2 * tok + 1];
    bool hit = (i0 == e) || (i1 == e);
    int kth = (i0 == e) ? 0 : 1;
    float g = gates[2 * tok + kth];
    unsigned long long m = __ballot(hit);
    int prefix = __popcll(m & ((1ull << lane) - 1ull));
    if (lane == 63) waveCnt[w] = prefix + (hit ? 1 : 0);
    __syncthreads();
    int off = runningS;
    for (int ww = 0; ww < w; ww++) off += waveCnt[ww];
    int pos = off + prefix;
    if (hit) {
      if (pos < CAP) {
        sel[e * CAP + pos] = tok; gsel[e * CAP + pos] = g;
        slot[2 * tok + kth] = pos;
      } else {
        slot[2 * tok + kth] = -1;
      }
    }
    __syncthreads();
    if (t == 0) {
      int sacc = 0;
#pragma unroll
      for (int ww = 0; ww < 16; ww++) sacc += waveCnt[ww];
      runningS += sacc;
    }
    __syncthreads();
  }
  for (int p = runningS + t; p < CAP; p += 1024) { sel[e * CAP + p] = 0; gsel[e * CAP + p] = 0.f; }
}

// ---------------- Transpose wp [E][1024][5460] f32 -> wpT [E][5460][1024] bf16 ----------------
__global__ void transpose_wp_kernel(const float* __restrict__ wp,
                                    unsigned short* __restrict__ wpT) {
  const int e = blockIdx.z, d0 = blockIdx.y * 32, f0 = blockIdx.x * 32;
  __shared__ unsigned short tile[32][33];
  const int t = threadIdx.x;
  {
    int ld = t >> 3, lf4 = (t & 7) * 4;
    if (f0 + lf4 < HFF2) {
      float4 v = *(const float4*)(wp + (size_t)e * DMODEL * HFF2 + (size_t)(d0 + ld) * HFF2 + f0 + lf4);
      tile[ld][lf4 + 0] = f2bf(v.x);
      tile[ld][lf4 + 1] = f2bf(v.y);
      tile[ld][lf4 + 2] = f2bf(v.z);
      tile[ld][lf4 + 3] = f2bf(v.w);
    }
  }
  __syncthreads();
  {
    int lf = t >> 3, ldq = (t & 7) * 4;
    if (f0 + lf < HFF2) {
      ushort4 o = make_ushort4(tile[ldq + 0][lf], tile[ldq + 1][lf],
                               tile[ldq + 2][lf], tile[ldq + 3][lf]);
      *(ushort4*)(wpT + (size_t)e * HFF2 * DMODEL + (size_t)(f0 + lf) * DMODEL + d0 + ldq) = o;
    }
  }
}

// ---------------- Transpose wd [E][2730][1024] f32 -> wdT [E][1024][2752] bf16 ----------------
__global__ void transpose_wd_kernel(const float* __restrict__ wd,
                                    unsigned short* __restrict__ wdT) {
  const int e = blockIdx.z, d0 = blockIdx.y * 32, k0 = blockIdx.x * 32;
  __shared__ unsigned short tile[32][33];
  const int t = threadIdx.x;
  {
    int lk = t >> 3, ld4 = (t & 7) * 4;
    int k = k0 + lk;
    if (k < HFF) {
      float4 v = *(const float4*)(wd + (size_t)e * HFF * DMODEL + (size_t)k * DMODEL + d0 + ld4);
      tile[lk][ld4 + 0] = f2bf(v.x);
      tile[lk][ld4 + 1] = f2bf(v.y);
      tile[lk][ld4 + 2] = f2bf(v.z);
      tile[lk][ld4 + 3] = f2bf(v.w);
    } else {
      tile[lk][ld4 + 0] = 0; tile[lk][ld4 + 1] = 0;
      tile[lk][ld4 + 2] = 0; tile[lk][ld4 + 3] = 0;
    }
  }
  __syncthreads();
  {
    int ld = t >> 3, lkq = (t & 7) * 4;
    ushort4 o = make_ushort4(tile[lkq + 0][ld], tile[lkq + 1][ld],
                             tile[lkq + 2][ld], tile[lkq + 3][ld]);
    *(ushort4*)(wdT + (size_t)e * DMODEL * KPAD + (size_t)(d0 + ld) * KPAD + k0 + lkq) = o;
  }
}

// ---------------- GEMM1: h = silu(X@wp1)*(X@wp2) ----------------
// 8-wave block, BM=256, BN=128 (per SwiGLU half), BK=32.
// LDS ring of 4 x 32KB buffers (128 KiB total, 1 block/CU).
// Pipeline: compute tile t while staging tile t+3 into the buffer last read
// at tile t-1 (reads drained by the tile-t top barrier -> race-free).
// Counted vmcnt(8) steady state (2 tiles x 4 loads in flight), never 0 in loop.
__global__ __launch_bounds__(512, 2)
void gemm1_kernel(const unsigned short* __restrict__ xb,
                  const unsigned short* __restrict__ wpT,
                  const int* __restrict__ sel,
                  unsigned short* __restrict__ h) {
  const int e = blockIdx.z;
  const int m0 = blockIdx.x * 256;
  const int n0 = blockIdx.y * 128;

  __shared__ __align__(16) unsigned short smem[4 * 16384];   // 128 KiB

  const int t = threadIdx.x;
  const int lane = t & 63;
  const int w = t >> 6;          // 0..7
  const int wr = w >> 2;         // 2-way M split (128 rows each)
  const int wc = w & 3;          // 4-way N split (32 cols each)
  const int fr = lane & 15;
  const int fq = lane >> 4;
  const int csw = (fq ^ ((fr >> 1) & 3)) * 8;      // swizzled read chunk (elems)

  // staging: thread t covers A rows r0 / r0+128, B1 row r0, B2 row r0
  const int r0 = t >> 2;                           // 0..127
  const int sw = ((t & 3) ^ ((t >> 3) & 3)) * 8;   // swizzled global seg (elems)
  const int tok0 = sel[e * CAP + m0 + r0];
  const int tok1 = sel[e * CAP + m0 + 128 + r0];
  const unsigned short* ga0 = xb + (size_t)tok0 * DMODEL + sw;
  const unsigned short* ga1 = xb + (size_t)tok1 * DMODEL + sw;
  const size_t ebase = (size_t)e * HFF2;
  int c0 = n0 + r0; if (c0 >= HFF) c0 = HFF - 1;   // dup rows; cols zeroed in epilogue
  const unsigned short* gb1 = wpT + (ebase + (size_t)c0) * DMODEL + sw;
  const unsigned short* gb2 = wpT + (ebase + (size_t)(HFF + c0)) * DMODEL + sw;

  const int dOff = w * 1024;     // bytes: wave-uniform LDS slice (16 rows/wave)

  f32x4 acc1[8][2], acc2[8][2];
#pragma unroll
  for (int i = 0; i < 8; i++)
#pragma unroll
    for (int j = 0; j < 2; j++) { acc1[i][j] = (f32x4)0.f; acc2[i][j] = (f32x4)0.f; }

  auto stageA = [&](int kt) {
    char* b = (char*)smem + (size_t)(kt & 3) * 32768;
    const int k0 = kt * 32;
    dma16(ga0 + k0, b + dOff);                 // A rows   0..127
    dma16(ga1 + k0, b + 8192 + dOff);          // A rows 128..255
  };
  auto stageB = [&](int kt) {
    char* b = (char*)smem + (size_t)(kt & 3) * 32768;
    const int k0 = kt * 32;
    dma16(gb1 + k0, b + 16384 + dOff);         // B1 rows 0..127
    dma16(gb2 + k0, b + 24576 + dOff);         // B2 rows 0..127
  };

  stageA(0); stageB(0); stageA(1); stageB(1); stageA(2); stageB(2);

  for (int kt = 0; kt < 32; ++kt) {
    if (kt < 30)       asm volatile("s_waitcnt vmcnt(8)" ::: "memory");
    else if (kt == 30) asm volatile("s_waitcnt vmcnt(4)" ::: "memory");
    else               asm volatile("s_waitcnt vmcnt(0)" ::: "memory");
    __builtin_amdgcn_s_barrier();
    asm volatile("" ::: "memory");   // keep LDS reads below the barrier

    const unsigned short* Ab  = smem + (kt & 3) * 16384;
    const unsigned short* B1b = Ab + 8192;
    const unsigned short* B2b = Ab + 12288;

    short8 a[8], b1[2], b2[2];
#pragma unroll
    for (int i = 0; i < 8; i++)
      a[i] = *(const short8*)(Ab + (wr * 128 + i * 16 + fr) * 32 + csw);
#pragma unroll
    for (int j = 0; j < 2; j++)
      b1[j] = *(const short8*)(B1b + (wc * 32 + j * 16 + fr) * 32 + csw);
    if (kt < 29) stageA(kt + 3);
    __builtin_amdgcn_s_setprio(1);
#pragma unroll
    for (int i = 0; i < 8; i++)
#pragma unroll
      for (int j = 0; j < 2; j++)
        acc1[i][j] = __builtin_amdgcn_mfma_f32_16x16x32_bf16(a[i], b1[j], acc1[i][j], 0, 0, 0);
    __builtin_amdgcn_s_setprio(0);
#pragma unroll
    for (int j = 0; j < 2; j++)
      b2[j] = *(const short8*)(B2b + (wc * 32 + j * 16 + fr) * 32 + csw);
    if (kt < 29) stageB(kt + 3);
    __builtin_amdgcn_s_setprio(1);
#pragma unroll
    for (int i = 0; i < 8; i++)
#pragma unroll
      for (int j = 0; j < 2; j++)
        acc2[i][j] = __builtin_amdgcn_mfma_f32_16x16x32_bf16(a[i], b2[j], acc2[i][j], 0, 0, 0);
    __builtin_amdgcn_s_setprio(0);
  }

#pragma unroll
  for (int i = 0; i < 8; i++) {
#pragma unroll
    for (int j = 0; j < 2; j++) {
      const int col = n0 + wc * 32 + j * 16 + fr;
      if (col < KPAD) {
#pragma unroll
        for (int r = 0; r < 4; r++) {
          const int row = m0 + wr * 128 + i * 16 + fq * 4 + r;
          float v1 = acc1[i][j][r], v2 = acc2[i][j][r];
          float hv = (col < HFF) ? (v1 / (1.f + __expf(-v1))) * v2 : 0.f;
          h[((size_t)e * CAP + row) * KPAD + col] = f2bf(hv);
        }
      }
    }
  }
}

// ---------------- GEMM2: contrib[e][slot] = h @ wd ----------------
// Same 8-wave ring pipeline; BM=256, BN=256, BK=32, K = KPAD = 86 tiles.
__global__ __launch_bounds__(512, 2)
void gemm2_kernel(const unsigned short* __restrict__ h,
                  const unsigned short* __restrict__ wdT,
                  unsigned short* __restrict__ contrib) {
  const int e = blockIdx.z;
  const int m0 = blockIdx.x * 256;
  const int n0 = blockIdx.y * 256;

  __shared__ __align__(16) unsigned short smem[4 * 16384];   // 128 KiB

  const int t = threadIdx.x;
  const int lane = t & 63;
  const int w = t >> 6;
  const int wr = w >> 2;         // 2-way M split (128 rows)
  const int wc = w & 3;          // 4-way N split (64 cols)
  const int fr = lane & 15;
  const int fq = lane >> 4;
  const int csw = (fq ^ ((fr >> 1) & 3)) * 8;

  const int r0 = t >> 2;
  const int sw = ((t & 3) ^ ((t >> 3) & 3)) * 8;
  const unsigned short* ga0 = h + ((size_t)e * CAP + m0 + r0) * KPAD + sw;
  const unsigned short* ga1 = h + ((size_t)e * CAP + m0 + 128 + r0) * KPAD + sw;
  const unsigned short* gb0 = wdT + ((size_t)e * DMODEL + n0 + r0) * KPAD + sw;
  const unsigned short* gb1 = wdT + ((size_t)e * DMODEL + n0 + 128 + r0) * KPAD + sw;

  const int dOff = w * 1024;

  f32x4 acc[8][4];
#pragma unroll
  for (int i = 0; i < 8; i++)
#pragma unroll
    for (int j = 0; j < 4; j++) acc[i][j] = (f32x4)0.f;

  auto stageA = [&](int kt) {
    char* b = (char*)smem + (size_t)(kt & 3) * 32768;
    const int k0 = kt * 32;
    dma16(ga0 + k0, b + dOff);                 // A rows   0..127
    dma16(ga1 + k0, b + 8192 + dOff);          // A rows 128..255
  };
  auto stageB = [&](int kt) {
    char* b = (char*)smem + (size_t)(kt & 3) * 32768;
    const int k0 = kt * 32;
    dma16(gb0 + k0, b + 16384 + dOff);         // B rows   0..127
    dma16(gb1 + k0, b + 24576 + dOff);         // B rows 128..255
  };

  stageA(0); stageB(0); stageA(1); stageB(1); stageA(2); stageB(2);

  for (int kt = 0; kt < 86; ++kt) {
    if (kt < 84)       asm volatile("s_waitcnt vmcnt(8)" ::: "memory");
    else if (kt == 84) asm volatile("s_waitcnt vmcnt(4)" ::: "memory");
    else               asm volatile("s_waitcnt vmcnt(0)" ::: "memory");
    __builtin_amdgcn_s_barrier();
    asm volatile("" ::: "memory");

    const unsigned short* Ab = smem + (kt & 3) * 16384;
    const unsigned short* Bb = Ab + 8192;

    short8 a[8], b[4];
#pragma unroll
    for (int i = 0; i < 8; i++)
      a[i] = *(const short8*)(Ab + (wr * 128 + i * 16 + fr) * 32 + csw);
#pragma unroll
    for (int j = 0; j < 4; j++)
      b[j] = *(const short8*)(Bb + (wc * 64 + j * 16 + fr) * 32 + csw);
    if (kt < 83) { stageA(kt + 3); stageB(kt + 3); }
    __builtin_amdgcn_s_setprio(1);
#pragma unroll
    for (int i = 0; i < 8; i++)
#pragma unroll
      for (int j = 0; j < 4; j++)
        acc[i][j] = __builtin_amdgcn_mfma_f32_16x16x32_bf16(a[i], b[j], acc[i][j], 0, 0, 0);
    __builtin_amdgcn_s_setprio(0);
  }

#pragma unroll
  for (int i = 0; i < 8; i++) {
#pragma unroll
    for (int j = 0; j < 4; j++) {
      const int col = n0 + wc * 64 + j * 16 + fr;
#pragma unroll
      for (int r = 0; r < 4; r++) {
        const int row = m0 + wr * 128 + i * 16 + fq * 4 + r;
        contrib[((size_t)e * CAP + row) * DMODEL + col] = f2bf(acc[i][j][r]);
      }
    }
  }
}

// ---------------- Combine: out[tok] = g0*contrib[e0][s0] + g1*contrib[e1][s1] ----------------
__global__ void combine_kernel(const unsigned short* __restrict__ contrib,
                               const int* __restrict__ topi,
                               const int* __restrict__ slot,
                               const float* __restrict__ gates,
                               float* __restrict__ out) {
  const int tok = blockIdx.x;
  const int t = threadIdx.x;
  const int e0 = topi[2 * tok], e1 = topi[2 * tok + 1];
  const int s0 = slot[2 * tok], s1 = slot[2 * tok + 1];
  const float g0 = gates[2 * tok], g1 = gates[2 * tok + 1];
  float4 acc = make_float4(0.f, 0.f, 0.f, 0.f);
  if (s0 >= 0) {
    ushort4 c = *(const ushort4*)(contrib + ((size_t)(e0 * CAP + s0)) * DMODEL + t * 4);
    acc.x += g0 * bf2f(c.x); acc.y += g0 * bf2f(c.y);
    acc.z += g0 * bf2f(c.z); acc.w += g0 * bf2f(c.w);
  }
  if (s1 >= 0) {
    ushort4 c = *(const ushort4*)(contrib + ((size_t)(e1 * CAP + s1)) * DMODEL + t * 4);
    acc.x += g1 * bf2f(c.x); acc.y += g1 * bf2f(c.y);
    acc.z += g1 * bf2f(c.z); acc.w += g1 * bf2f(c.w);
  }
  *(float4*)(out + (size_t)tok * DMODEL + t * 4) = acc;
}

// ---------------- launch ----------------
extern "C" void kernel_launch(void* const* d_in, const int* in_sizes, int n_in,
                              void* d_out, int out_size, void* d_ws, size_t ws_size,
                              hipStream_t stream) {
  const float* x = (const float*)d_in[0];
  const float* noise = (const float*)d_in[1];
  const float* w_route = (const float*)d_in[2];
  const float* b_route = (const float*)d_in[3];
  const float* w_noise = (const float*)d_in[4];
  const float* b_noise = (const float*)d_in[5];
  const float* w_proj = (const float*)d_in[6];
  const float* w_down = (const float*)d_in[7];
  float* out = (float*)d_out;

  char* ws = (char*)d_ws;
  const size_t WT_BYTES = (size_t)NEXP * HFF2 * DMODEL * 2;   // 89.4 MB (wpT; later wdT+contrib)
  const size_t WDT_BYTES = (size_t)NEXP * DMODEL * KPAD * 2;  // 45.1 MB
  const size_t H_BYTES = (size_t)NEXP * CAP * KPAD * 2;       // 90.2 MB
  unsigned short* wT = (unsigned short*)ws;
  unsigned short* contrib = (unsigned short*)(ws + WDT_BYTES);  // 33.5 MB, dead tail of wT region
  unsigned short* hbuf = (unsigned short*)(ws + WT_BYTES);
  char* p = ws + WT_BYTES + H_BYTES;
  int* sel = (int*)p;          p += (size_t)NEXP * CAP * 4;
  float* gsel = (float*)p;     p += (size_t)NEXP * CAP * 4;
  int* topi = (int*)p;         p += (size_t)NTOK * 2 * 4;
  float* gates = (float*)p;    p += (size_t)NTOK * 2 * 4;
  int* slot = (int*)p;

  // xb (bf16 x, 16.8 MB) lives in d_out until gemm1 done; combine overwrites out fully.
  unsigned short* xb = (unsigned short*)d_out;

  hipLaunchKernelGGL(cast_x_kernel, dim3(NTOK * DMODEL / (256 * 8)), dim3(256), 0, stream, x, xb);
  hipLaunchKernelGGL(router_kernel, dim3(NTOK / 4), dim3(256), 0, stream,
                     x, noise, w_route, b_route, w_noise, b_noise, topi, gates);
  hipLaunchKernelGGL(dispatch_kernel, dim3(NEXP), dim3(1024), 0, stream, topi, gates, sel, gsel, slot);
  hipLaunchKernelGGL(transpose_wp_kernel, dim3(171, 32, NEXP), dim3(256), 0, stream, w_proj, wT);
  hipLaunchKernelGGL(gemm1_kernel, dim3(CAP / 256, 22, NEXP), dim3(512), 0, stream, xb, wT, sel, hbuf);
  hipLaunchKernelGGL(transpose_wd_kernel, dim3(KPAD / 32, DMODEL / 32, NEXP), dim3(256), 0, stream, w_down, wT);
  hipLaunchKernelGGL(gemm2_kernel, dim3(CAP / 256, DMODEL / 256, NEXP), dim3(512), 0, stream,
                     hbuf, wT, contrib);
  hipLaunchKernelGGL(combine_kernel, dim3(NTOK), dim3(256), 0, stream,
                     contrib, topi, slot, gates, out);
  hipLaunchKernelGGL(aux_kernel, dim3(1), dim3(256), 0, stream, topi, gates, out);
}